// Round 7
// baseline (282.215 us; speedup 1.0000x reference)
//
#include <hip/hip_runtime.h>

#define E_DIM 1024

typedef __attribute__((ext_vector_type(8))) short bf16x8;
typedef __attribute__((ext_vector_type(4))) float f32x4;
typedef unsigned long long u64;

// ---- monotone float->uint so unsigned min == float min ----
__device__ __forceinline__ unsigned f2mono(float f) {
  unsigned u = __float_as_uint(f);
  return (u & 0x80000000u) ? ~u : (u | 0x80000000u);
}
// pack two fp32 into bf16x2 (truncation) with one v_perm_b32 (fallback path)
__device__ __forceinline__ unsigned pk_bf16(float lo, float hi) {
  return __builtin_amdgcn_perm(__float_as_uint(hi), __float_as_uint(lo), 0x07060302u);
}
// async global->LDS, 16B per lane: lds image = lane-ordered copy of 1KB/wave
__device__ __forceinline__ void dma16(const void* g, void* l) {
  __builtin_amdgcn_global_load_lds(
      (const __attribute__((address_space(1))) unsigned*)g,
      (__attribute__((address_space(3))) unsigned*)l, 16, 0, 0);
}

// Kernel 1: per-row inverse norms, exact ap_i, init both top-2 arrays.
__global__ __launch_bounds__(256) void norms_kernel(
    const float* __restrict__ A, const float* __restrict__ P,
    float* __restrict__ inv_na, float* __restrict__ inv_np,
    float* __restrict__ ap, u64* __restrict__ arr1, u64* __restrict__ arr2) {
  const int row = blockIdx.x;
  const int t = threadIdx.x;
  const float4* a4 = (const float4*)(A + (size_t)row * E_DIM);
  const float4* p4 = (const float4*)(P + (size_t)row * E_DIM);
  float sa = 0.f, sp = 0.f, sab = 0.f;
  for (int c = t; c < E_DIM / 4; c += 256) {
    float4 a = a4[c];
    float4 p = p4[c];
    sa  += a.x * a.x + a.y * a.y + a.z * a.z + a.w * a.w;
    sp  += p.x * p.x + p.y * p.y + p.z * p.z + p.w * p.w;
    sab += a.x * p.x + a.y * p.y + a.z * p.z + a.w * p.w;
  }
#pragma unroll
  for (int off = 32; off > 0; off >>= 1) {
    sa  += __shfl_down(sa, off);
    sp  += __shfl_down(sp, off);
    sab += __shfl_down(sab, off);
  }
  __shared__ float red[4][3];
  const int wave = t >> 6, lane = t & 63;
  if (lane == 0) { red[wave][0] = sa; red[wave][1] = sp; red[wave][2] = sab; }
  __syncthreads();
  if (t == 0) {
    sa  = red[0][0] + red[1][0] + red[2][0] + red[3][0];
    sp  = red[0][1] + red[1][1] + red[2][1] + red[3][1];
    sab = red[0][2] + red[1][2] + red[2][2] + red[3][2];
    float ina = 1.0f / sqrtf(sa);
    float inp = 1.0f / sqrtf(sp);
    inv_na[row] = ina;
    inv_np[row] = inp;
    ap[row] = sab * ina * inp;
    arr1[row] = 0xFFFFFFFFFFFFFFFFULL;
    arr2[row] = 0xFFFFFFFFFFFFFFFFULL;
  }
}

// Kernel 1b: fp32 -> fp8 e4m3 tiled convert, both matrices in one launch.
// Chunk = (row_block rb of 128 rows, k-chunk kb of 32). 4KB chunk layout:
// bytes[(q*128 + row)*8 + j], q=(k%32)/8, j=k%8 — the MFMA fragment order,
// so the GEMM's DMA produces a directly-readable LDS image.
__global__ __launch_bounds__(256) void convert_fp8(
    const float* __restrict__ A, const float* __restrict__ P,
    unsigned char* __restrict__ At, unsigned char* __restrict__ Pt,
    int nchunk) {
  const int b = blockIdx.x;
  const float* X = (b < nchunk) ? A : P;
  unsigned char* Xt = (b < nchunk) ? At : Pt;
  const int cb = (b < nchunk) ? b : b - nchunk;
  const int rb = cb >> 5;
  const int kb = cb & 31;
  const int t = threadIdx.x;
  const int row = t >> 1;
  const int half = t & 1;  // which 16-k half of the 32-k chunk
  const float* src = X + (size_t)(rb * 128 + row) * E_DIM + kb * 32 + half * 16;
  float4 v0 = ((const float4*)src)[0];
  float4 v1 = ((const float4*)src)[1];
  float4 v2 = ((const float4*)src)[2];
  float4 v3 = ((const float4*)src)[3];
  int d0 = __builtin_amdgcn_cvt_pk_fp8_f32(v0.x, v0.y, 0, 0);
  d0 = __builtin_amdgcn_cvt_pk_fp8_f32(v0.z, v0.w, d0, 1);
  int d1 = __builtin_amdgcn_cvt_pk_fp8_f32(v1.x, v1.y, 0, 0);
  d1 = __builtin_amdgcn_cvt_pk_fp8_f32(v1.z, v1.w, d1, 1);
  int e0 = __builtin_amdgcn_cvt_pk_fp8_f32(v2.x, v2.y, 0, 0);
  e0 = __builtin_amdgcn_cvt_pk_fp8_f32(v2.z, v2.w, e0, 1);
  int e1 = __builtin_amdgcn_cvt_pk_fp8_f32(v3.x, v3.y, 0, 0);
  e1 = __builtin_amdgcn_cvt_pk_fp8_f32(v3.z, v3.w, e1, 1);
  unsigned char* base = Xt + (size_t)cb * 4096;
  uint2 lo = {(unsigned)d0, (unsigned)d1};  // q = 2*half, j=0..7
  uint2 hi = {(unsigned)e0, (unsigned)e1};  // q = 2*half+1
  *(uint2*)(base + ((2 * half + 0) * 128 + row) * 8) = lo;
  *(uint2*)(base + ((2 * half + 1) * 128 + row) * 8) = hi;
}

// Kernel 2: fp8 MFMA GEMM dot = A P^T from pre-tiled fp8 operands.
// 128x128 tile, 4 waves (2x2 of 64x64), BK=128 (4 chunks per matrix per iter,
// 8 barrier windows total, 64 MFMA/wave/window), staging via global_load_lds
// width=16. XCD-aware 8x8 supertile swizzle (R6-proven). Fused per-row TOP-2
// (value,index) of dot*inv_np[col], j != i, merged globally via the two-stage
// atomicMin displacement trick (loser of the arr1 battle -> arr2, which
// provably captures the global 2nd-min). Exact values repaired by an2_kernel.
__global__ __launch_bounds__(256) void simmin_fp8(
    const unsigned char* __restrict__ At, const unsigned char* __restrict__ Pt,
    const float* __restrict__ inv_np, u64* __restrict__ arr1,
    u64* __restrict__ arr2, int nb) {
  __shared__ __align__(16) unsigned char As[16384];  // 4 chunks of 4KB
  __shared__ __align__(16) unsigned char Ps[16384];

  const int lid = blockIdx.x;
  int by, bx;
  if (nb == 64) {  // B=8192: 8x8 supertiles of 8x8 blocks, one supertile/XCD
    const int xcd = lid & 7;
    const int s = lid >> 3;
    const int st = xcd * 8 + (s >> 6);
    const int u = s & 63;
    by = (st >> 3) * 8 + (u >> 3);
    bx = (st & 7) * 8 + (u & 7);
  } else {
    by = lid / nb;
    bx = lid % nb;
  }

  const int tid = threadIdx.x;
  const int wave = tid >> 6, lane = tid & 63;
  const int wr = wave >> 1, wc = wave & 1;
  const int rowBase = by * 128;
  const int colBase = bx * 128;
  const int c = lane & 15, q = lane >> 4;

  f32x4 acc[4][4];
#pragma unroll
  for (int mt = 0; mt < 4; ++mt)
#pragma unroll
    for (int nt = 0; nt < 4; ++nt) acc[mt][nt] = (f32x4){0.f, 0.f, 0.f, 0.f};

  const unsigned char* Ab = At + (size_t)by * (32 * 4096);  // 128KB slab
  const unsigned char* Pb = Pt + (size_t)bx * (32 * 4096);
  const int loff = wave * 4096;       // each wave stages one 4KB chunk
  const int goff = loff + lane * 16;

  // fragment byte-offsets within a 4KB chunk: [(q*128 + tile_row)*8 + j]
  const int aidx = (q * 128 + wr * 64 + c) * 8;
  const int bidx = (q * 128 + wc * 64 + c) * 8;

  for (int kt = 0; kt < 8; ++kt) {  // BK=128
    const unsigned char* ca = Ab + kt * 16384;
    const unsigned char* cp = Pb + kt * 16384;
    dma16(ca + goff, As + loff);
    dma16(ca + goff + 1024, As + loff + 1024);
    dma16(ca + goff + 2048, As + loff + 2048);
    dma16(ca + goff + 3072, As + loff + 3072);
    dma16(cp + goff, Ps + loff);
    dma16(cp + goff + 1024, Ps + loff + 1024);
    dma16(cp + goff + 2048, Ps + loff + 2048);
    dma16(cp + goff + 3072, Ps + loff + 3072);
    __syncthreads();  // vmcnt(0) drain + barrier

#pragma unroll
    for (int kk = 0; kk < 4; ++kk) {
      u64 af[4], bfr[4];
#pragma unroll
      for (int mt = 0; mt < 4; ++mt)
        af[mt] = *(const u64*)&As[kk * 4096 + aidx + mt * 128];
#pragma unroll
      for (int nt = 0; nt < 4; ++nt)
        bfr[nt] = *(const u64*)&Ps[kk * 4096 + bidx + nt * 128];
#pragma unroll
      for (int mt = 0; mt < 4; ++mt)
#pragma unroll
        for (int nt = 0; nt < 4; ++nt)
          acc[mt][nt] = __builtin_amdgcn_mfma_f32_16x16x32_fp8_fp8(
              (long)af[mt], (long)bfr[nt], acc[mt][nt], 0, 0, 0);
    }
    __syncthreads();
  }

  // Epilogue: per-row top-2 of v = dot*inv_np[col], j != i.
  // C/D layout: col = lane&15 (=c), row = q*4 + reg.
  float inp_l[4];
#pragma unroll
  for (int nt = 0; nt < 4; ++nt)
    inp_l[nt] = inv_np[colBase + wc * 64 + nt * 16 + c];

#pragma unroll
  for (int mt = 0; mt < 4; ++mt) {
#pragma unroll
    for (int reg = 0; reg < 4; ++reg) {
      const int gi = rowBase + wr * 64 + mt * 16 + q * 4 + reg;
      float v1 = 3.4e38f, v2 = 3.4e38f;
      int i1 = 0, i2 = 0;
#pragma unroll
      for (int nt = 0; nt < 4; ++nt) {
        const int gj = colBase + wc * 64 + nt * 16 + c;
        float v = acc[mt][nt][reg] * inp_l[nt];
        if (gj != gi) {
          if (v < v1) { v2 = v1; i2 = i1; v1 = v; i1 = gj; }
          else if (v < v2) { v2 = v; i2 = gj; }
        }
      }
      // merge (1st,2nd) pairs across the 16 c-lanes
#pragma unroll
      for (int off = 1; off < 16; off <<= 1) {
        float ov1 = __shfl_xor(v1, off); int oi1 = __shfl_xor(i1, off);
        float ov2 = __shfl_xor(v2, off); int oi2 = __shfl_xor(i2, off);
        float l; int li;
        if (ov1 < v1) { l = v1; li = i1; v1 = ov1; i1 = oi1; }
        else          { l = ov1; li = oi1; }
        if (ov2 < v2) { v2 = ov2; i2 = oi2; }
        if (l < v2)   { v2 = l; i2 = li; }
      }
      if (c == 0) {
        u64 p1 = ((u64)f2mono(v1) << 32) | (unsigned)i1;
        u64 p2 = ((u64)f2mono(v2) << 32) | (unsigned)i2;
        u64 old = atomicMin(&arr1[gi], p1);
        u64 l2 = (old < p1) ? p1 : old;   // loser of the arr1 battle
        if (p2 < l2) l2 = p2;
        atomicMin(&arr2[gi], l2);
      }
    }
  }
}

// Fallback GEMM (round-3 proven, bf16 top-1): used only if ws too small.
__global__ __launch_bounds__(256) void simmin_mfma(
    const float* __restrict__ A, const float* __restrict__ P,
    const float* __restrict__ inv_np, u64* __restrict__ min64) {
  __shared__ __align__(16) short As[128 * 40];
  __shared__ __align__(16) short Ps[128 * 40];

  const int tid = threadIdx.x;
  const int wave = tid >> 6, lane = tid & 63;
  const int wr = wave >> 1, wc = wave & 1;
  const int rowBase = blockIdx.y * 128;
  const int colBase = blockIdx.x * 128;
  const int c = lane & 15, q = lane >> 4;

  f32x4 acc[4][4];
#pragma unroll
  for (int mt = 0; mt < 4; ++mt)
#pragma unroll
    for (int nt = 0; nt < 4; ++nt) acc[mt][nt] = (f32x4){0.f, 0.f, 0.f, 0.f};

  const int sm = tid >> 1;
  const int sh = (tid & 1) * 16;
  const float* Ab = A + (size_t)(rowBase + sm) * E_DIM + sh;
  const float* Pb = P + (size_t)(colBase + sm) * E_DIM + sh;
  uint4* AsW = (uint4*)&As[sm * 40 + sh];
  uint4* PsW = (uint4*)&Ps[sm * 40 + sh];

  for (int kt = 0; kt < E_DIM; kt += 32) {
    float4 a0 = *(const float4*)(Ab + kt);
    float4 a1 = *(const float4*)(Ab + kt + 4);
    float4 a2 = *(const float4*)(Ab + kt + 8);
    float4 a3 = *(const float4*)(Ab + kt + 12);
    float4 p0 = *(const float4*)(Pb + kt);
    float4 p1 = *(const float4*)(Pb + kt + 4);
    float4 p2 = *(const float4*)(Pb + kt + 8);
    float4 p3 = *(const float4*)(Pb + kt + 12);
    uint4 av0 = {pk_bf16(a0.x, a0.y), pk_bf16(a0.z, a0.w),
                 pk_bf16(a1.x, a1.y), pk_bf16(a1.z, a1.w)};
    uint4 av1 = {pk_bf16(a2.x, a2.y), pk_bf16(a2.z, a2.w),
                 pk_bf16(a3.x, a3.y), pk_bf16(a3.z, a3.w)};
    uint4 pv0 = {pk_bf16(p0.x, p0.y), pk_bf16(p0.z, p0.w),
                 pk_bf16(p1.x, p1.y), pk_bf16(p1.z, p1.w)};
    uint4 pv1 = {pk_bf16(p2.x, p2.y), pk_bf16(p2.z, p2.w),
                 pk_bf16(p3.x, p3.y), pk_bf16(p3.z, p3.w)};
    AsW[0] = av0; AsW[1] = av1;
    PsW[0] = pv0; PsW[1] = pv1;
    __syncthreads();

    bf16x8 af[4], bfr[4];
#pragma unroll
    for (int mt = 0; mt < 4; ++mt)
      af[mt] = *(const bf16x8*)&As[(wr * 64 + mt * 16 + c) * 40 + q * 8];
#pragma unroll
    for (int nt = 0; nt < 4; ++nt)
      bfr[nt] = *(const bf16x8*)&Ps[(wc * 64 + nt * 16 + c) * 40 + q * 8];
#pragma unroll
    for (int mt = 0; mt < 4; ++mt)
#pragma unroll
      for (int nt = 0; nt < 4; ++nt)
        acc[mt][nt] = __builtin_amdgcn_mfma_f32_16x16x32_bf16(
            af[mt], bfr[nt], acc[mt][nt], 0, 0, 0);
    __syncthreads();
  }

  float inp_l[4];
#pragma unroll
  for (int nt = 0; nt < 4; ++nt)
    inp_l[nt] = inv_np[colBase + wc * 64 + nt * 16 + c];

#pragma unroll
  for (int mt = 0; mt < 4; ++mt) {
#pragma unroll
    for (int reg = 0; reg < 4; ++reg) {
      const int gi = rowBase + wr * 64 + mt * 16 + q * 4 + reg;
      float best = 3.4e38f;
      int bidx2 = 0;
#pragma unroll
      for (int nt = 0; nt < 4; ++nt) {
        const int gj = colBase + wc * 64 + nt * 16 + c;
        float v = acc[mt][nt][reg] * inp_l[nt];
        if (gj != gi && v < best) { best = v; bidx2 = gj; }
      }
#pragma unroll
      for (int off = 1; off < 16; off <<= 1) {
        float ov = __shfl_xor(best, off);
        int oi = __shfl_xor(bidx2, off);
        if (ov < best) { best = ov; bidx2 = oi; }
      }
      if (c == 0) {
        u64 pk = ((u64)f2mono(best) << 32) | (unsigned)bidx2;
        atomicMin(&min64[gi], pk);
      }
    }
  }
}

// Kernel 3: exact fp32 cos for BOTH top-2 candidates; an = min of the two.
__global__ __launch_bounds__(256) void an2_kernel(
    const float* __restrict__ A, const float* __restrict__ P,
    const float* __restrict__ inv_na, const float* __restrict__ inv_np,
    const u64* __restrict__ arr1, const u64* __restrict__ arr2,
    float* __restrict__ an, int B) {
  const int row = blockIdx.x;
  const int t = threadIdx.x;
  const unsigned j1 = (unsigned)(arr1[row] & 0xFFFFFFFFULL) & (unsigned)(B - 1);
  const unsigned j2 = (unsigned)(arr2[row] & 0xFFFFFFFFULL) & (unsigned)(B - 1);
  const float4* a4 = (const float4*)(A + (size_t)row * E_DIM);
  const float4* p4a = (const float4*)(P + (size_t)j1 * E_DIM);
  const float4* p4b = (const float4*)(P + (size_t)j2 * E_DIM);
  float s1 = 0.f, s2 = 0.f;
  for (int ci = t; ci < E_DIM / 4; ci += 256) {
    float4 a = a4[ci];
    float4 p = p4a[ci];
    float4 r = p4b[ci];
    s1 += a.x * p.x + a.y * p.y + a.z * p.z + a.w * p.w;
    s2 += a.x * r.x + a.y * r.y + a.z * r.z + a.w * r.w;
  }
#pragma unroll
  for (int off = 32; off > 0; off >>= 1) {
    s1 += __shfl_down(s1, off);
    s2 += __shfl_down(s2, off);
  }
  __shared__ float red[4][2];
  const int wave = t >> 6, lane = t & 63;
  if (lane == 0) { red[wave][0] = s1; red[wave][1] = s2; }
  __syncthreads();
  if (t == 0) {
    s1 = red[0][0] + red[1][0] + red[2][0] + red[3][0];
    s2 = red[0][1] + red[1][1] + red[2][1] + red[3][1];
    float ina = inv_na[row];
    float c1 = s1 * ina * inv_np[j1];
    float c2 = s2 * ina * inv_np[j2];
    an[row] = (c1 < c2) ? c1 : c2;
  }
}

// Kernel 4: loss_i = relu(1 + ap_i - an_i); out = mean.
__global__ __launch_bounds__(256) void loss_kernel(
    const float* __restrict__ ap, const float* __restrict__ an,
    float* __restrict__ out, int B) {
  const int t = threadIdx.x;
  float s = 0.f;
  for (int i = t; i < B; i += 256) {
    float l = 1.0f + ap[i] - an[i];
    s += (l > 0.f) ? l : 0.f;
  }
#pragma unroll
  for (int off = 32; off > 0; off >>= 1) s += __shfl_down(s, off);
  __shared__ float red[4];
  const int wave = t >> 6, lane = t & 63;
  if (lane == 0) red[wave] = s;
  __syncthreads();
  if (t == 0) out[0] = (red[0] + red[1] + red[2] + red[3]) / (float)B;
}

extern "C" void kernel_launch(void* const* d_in, const int* in_sizes, int n_in,
                              void* d_out, int out_size, void* d_ws, size_t ws_size,
                              hipStream_t stream) {
  const float* A = (const float*)d_in[0];  // anchor  [B][1024] fp32
  const float* P = (const float*)d_in[1];  // positive[B][1024] fp32
  const int B = in_sizes[0] / E_DIM;       // 8192

  const size_t fp8_elems = (size_t)B * E_DIM;  // bytes per fp8 matrix
  const size_t need = 2 * fp8_elems + (size_t)B * (16 + 16) + 64;
  const int nb = B / 128;

  if (ws_size >= need) {
    unsigned char* At = (unsigned char*)d_ws;
    unsigned char* Pt = At + fp8_elems;
    u64* arr1 = (u64*)(Pt + fp8_elems);   // 8B-aligned (16MB offset)
    u64* arr2 = arr1 + B;
    float* inv_na = (float*)(arr2 + B);
    float* inv_np = inv_na + B;
    float* ap = inv_np + B;
    float* an = ap + B;
    const int nchunk = nb * 32;

    norms_kernel<<<B, 256, 0, stream>>>(A, P, inv_na, inv_np, ap, arr1, arr2);
    convert_fp8<<<2 * nchunk, 256, 0, stream>>>(A, P, At, Pt, nchunk);
    simmin_fp8<<<nb * nb, 256, 0, stream>>>(At, Pt, inv_np, arr1, arr2, nb);
    an2_kernel<<<B, 256, 0, stream>>>(A, P, inv_na, inv_np, arr1, arr2, an, B);
    loss_kernel<<<1, 256, 0, stream>>>(ap, an, (float*)d_out, B);
  } else {
    float* inv_na = (float*)d_ws;
    float* inv_np = inv_na + B;
    float* ap = inv_np + B;
    float* an = ap + B;
    u64* min64 = (u64*)(an + B);
    dim3 grid(nb, nb);

    norms_kernel<<<B, 256, 0, stream>>>(A, P, inv_na, inv_np, ap, min64, min64);
    simmin_mfma<<<grid, 256, 0, stream>>>(A, P, inv_np, min64);
    an2_kernel<<<B, 256, 0, stream>>>(A, P, inv_na, inv_np, min64, min64, an, B);
    loss_kernel<<<1, 256, 0, stream>>>(ap, an, (float*)d_out, B);
  }
}